// Round 2
// baseline (883.533 us; speedup 1.0000x reference)
//
#include <hip/hip_runtime.h>
#include <hip/hip_bf16.h>

#define N_NODES   100000
#define N_EDGES   1600000
#define FDIM      128
#define N_GRAPHS  64
#define N_CLASSES 32

// ---------------- degree count ----------------
__global__ __launch_bounds__(256) void deg_kernel(const int* __restrict__ dst, int* __restrict__ degi, int nE) {
    int e = blockIdx.x * 256 + threadIdx.x;
    if (e < nE) atomicAdd(&degi[dst[e]], 1);
}

// ---------------- dinv = rsqrt(deg+1) ----------------
__global__ __launch_bounds__(256) void dinv_kernel(const int* __restrict__ degi, float* __restrict__ dinv) {
    int i = blockIdx.x * 256 + threadIdx.x;
    if (i < N_NODES) dinv[i] = rsqrtf((float)degi[i] + 1.0f);
}

// ---------------- exclusive prefix scan over degi -> row_ptr, cursor ----------------
__global__ __launch_bounds__(1024) void scan_kernel(const int* __restrict__ degi,
                                                    int* __restrict__ row_ptr,
                                                    int* __restrict__ cursor, int nE) {
    __shared__ int buf[1024];
    __shared__ int carry_s;
    int t = threadIdx.x;
    if (t == 0) carry_s = 0;
    for (int base = 0; base < N_NODES; base += 1024) {
        __syncthreads();
        int c = carry_s;
        int i = base + t;
        int v = (i < N_NODES) ? degi[i] : 0;
        buf[t] = v;
        __syncthreads();
        int x = v;
        #pragma unroll
        for (int off = 1; off < 1024; off <<= 1) {
            int y = (t >= off) ? buf[t - off] : 0;
            __syncthreads();
            x += y;
            buf[t] = x;
            __syncthreads();
        }
        if (i < N_NODES) {
            int rp = c + x - v;   // exclusive
            row_ptr[i] = rp;
            cursor[i]  = rp;
        }
        __syncthreads();
        if (t == 0) carry_s = c + buf[1023];
    }
    if (t == 0) row_ptr[N_NODES] = nE;
}

// ---------------- counting-sort edges by dst ----------------
__global__ __launch_bounds__(256) void sort_kernel(const int* __restrict__ src, const int* __restrict__ dst,
                                                   int* __restrict__ cursor, int* __restrict__ esrc, int nE) {
    int e = blockIdx.x * 256 + threadIdx.x;
    if (e < nE) {
        int d = dst[e];
        int pos = atomicAdd(&cursor[d], 1);
        esrc[pos] = src[e];
    }
}

// ---------------- f32 GEMM: C[n x 128] = X[n x 128] @ W[128 x 128] ----------------
// block 256 threads, tile 64 rows x 128 cols; thread: 8 rows x 4 cols
__global__ __launch_bounds__(256) void gemm128(const float* __restrict__ X, const float* __restrict__ W,
                                               float* __restrict__ C, int nrows) {
    __shared__ float xs[64 * 128];
    int t = threadIdx.x;
    long long base = (long long)blockIdx.x * 64;
    int valid = nrows - (int)base; if (valid > 64) valid = 64;
    int nelem = valid * 128;
    #pragma unroll
    for (int i = 0; i < 8; ++i) {
        int idx4 = i * 256 + t;
        int idx  = idx4 * 4;
        float4 v = make_float4(0.f, 0.f, 0.f, 0.f);
        if (idx < nelem) v = *(const float4*)(X + base * 128 + idx);
        *(float4*)(xs + idx) = v;
    }
    __syncthreads();
    int tc = t & 31;   // col group (4 cols)
    int tr = t >> 5;   // row group (8 rows)
    int c0 = tc * 4;
    float acc[8][4];
    #pragma unroll
    for (int r = 0; r < 8; ++r)
        #pragma unroll
        for (int c = 0; c < 4; ++c) acc[r][c] = 0.f;
    #pragma unroll 8
    for (int k = 0; k < 128; ++k) {
        float4 wv = *(const float4*)(W + k * 128 + c0);
        #pragma unroll
        for (int r = 0; r < 8; ++r) {
            float xv = xs[(tr * 8 + r) * 128 + k];
            acc[r][0] += xv * wv.x;
            acc[r][1] += xv * wv.y;
            acc[r][2] += xv * wv.z;
            acc[r][3] += xv * wv.w;
        }
    }
    #pragma unroll
    for (int r = 0; r < 8; ++r) {
        long long row = base + tr * 8 + r;
        if (row < nrows)
            *(float4*)(C + row * 128 + c0) = make_float4(acc[r][0], acc[r][1], acc[r][2], acc[r][3]);
    }
}

// ---------------- aggregation: O = relu( D^-1/2 (A+I) D^-1/2 H + b ) ----------------
// one wave per node; lane handles 2 features (float2)
__global__ __launch_bounds__(256) void agg_kernel(const float* __restrict__ H, float* __restrict__ O,
                                                  const float* __restrict__ dinv,
                                                  const int* __restrict__ row_ptr,
                                                  const int* __restrict__ esrc,
                                                  const float* __restrict__ bias) {
    int node = blockIdx.x * 4 + (threadIdx.x >> 6);
    if (node >= N_NODES) return;
    int lane = threadIdx.x & 63;
    float dv = dinv[node];
    float2 hv = *((const float2*)(H + (long long)node * FDIM) + lane);
    float sw = dv * dv;
    float ax = hv.x * sw, ay = hv.y * sw;
    int beg = row_ptr[node], end = row_ptr[node + 1];
    int sNext = (beg < end) ? esrc[beg] : 0;
    for (int e = beg; e < end; ++e) {
        int s = sNext;
        if (e + 1 < end) sNext = esrc[e + 1];
        float w = dinv[s] * dv;
        float2 m = *((const float2*)(H + (long long)s * FDIM) + lane);
        ax += m.x * w;
        ay += m.y * w;
    }
    float2 bb = *((const float2*)bias + lane);
    ax += bb.x; ay += bb.y;
    ax = fmaxf(ax, 0.f); ay = fmaxf(ay, 0.f);
    *((float2*)(O + (long long)node * FDIM) + lane) = make_float2(ax, ay);
}

// ---------------- pooling: per-graph feature sums + counts (batch sorted) ----------------
__global__ __launch_bounds__(128) void pool_kernel(const float* __restrict__ H, const int* __restrict__ batch,
                                                   float* __restrict__ pooled, float* __restrict__ cnt) {
    int f  = threadIdx.x;           // 0..127
    int r0 = blockIdx.x * 128;
    int rend = r0 + 128; if (rend > N_NODES) rend = N_NODES;
    if (r0 >= N_NODES) return;
    float acc = 0.f;
    int g_cur = batch[r0];
    int run = 0;
    for (int r = r0; r < rend; ++r) {
        int g = batch[r];
        if (g != g_cur) {
            atomicAdd(&pooled[g_cur * FDIM + f], acc);
            if (f == 0) atomicAdd(&cnt[g_cur], (float)run);
            acc = 0.f; run = 0; g_cur = g;
        }
        acc += H[(long long)r * FDIM + f];
        run++;
    }
    atomicAdd(&pooled[g_cur * FDIM + f], acc);
    if (f == 0) atomicAdd(&cnt[g_cur], (float)run);
}

// ---------------- final FC: out[g][c] = (pooled[g]/max(cnt,1)) . fcW[:,c] + fcb[c] ----------------
__global__ __launch_bounds__(256) void fc_kernel(const float* __restrict__ pooled, const float* __restrict__ cnt,
                                                 const float* __restrict__ fcW, const float* __restrict__ fcb,
                                                 float* __restrict__ out) {
    int idx = blockIdx.x * 256 + threadIdx.x;
    if (idx >= N_GRAPHS * N_CLASSES) return;
    int g = idx >> 5, c = idx & 31;
    float inv = 1.0f / fmaxf(cnt[g], 1.0f);
    float acc = 0.f;
    #pragma unroll 16
    for (int k = 0; k < FDIM; ++k) acc += pooled[g * FDIM + k] * fcW[k * N_CLASSES + c];
    out[idx] = acc * inv + fcb[c];
}

extern "C" void kernel_launch(void* const* d_in, const int* in_sizes, int n_in,
                              void* d_out, int out_size, void* d_ws, size_t ws_size,
                              hipStream_t stream) {
    const float* x    = (const float*)d_in[0];
    const int*   ei   = (const int*)d_in[1];     // [2, E] int32
    const int*   batch= (const int*)d_in[2];
    const float* W1   = (const float*)d_in[3];
    const float* b1   = (const float*)d_in[4];
    const float* W2   = (const float*)d_in[5];
    const float* b2   = (const float*)d_in[6];
    const float* fcW  = (const float*)d_in[7];
    const float* fcb  = (const float*)d_in[8];
    float* out = (float*)d_out;

    const int nE = in_sizes[1] / 2;              // robust to harness count
    const int* src = ei;
    const int* dst = ei + nE;

    // workspace layout
    float* A      = (float*)d_ws;                       // N*F
    float* B      = A + (long long)N_NODES * FDIM;      // N*F
    float* dinv   = B + (long long)N_NODES * FDIM;      // N
    int*   degi   = (int*)(dinv + N_NODES);             // N
    int*   row_ptr= degi + N_NODES;                     // N+1
    int*   cursor = row_ptr + N_NODES + 1;              // N
    int*   esrc   = cursor + N_NODES;                   // E
    float* pooled = (float*)(esrc + nE);                // G*F
    float* cnt    = pooled + N_GRAPHS * FDIM;           // G

    hipMemsetAsync(degi, 0, N_NODES * sizeof(int), stream);
    hipMemsetAsync(pooled, 0, (N_GRAPHS * FDIM + N_GRAPHS) * sizeof(float), stream);

    deg_kernel<<<(nE + 255) / 256, 256, 0, stream>>>(dst, degi, nE);
    dinv_kernel<<<(N_NODES + 255) / 256, 256, 0, stream>>>(degi, dinv);
    scan_kernel<<<1, 1024, 0, stream>>>(degi, row_ptr, cursor, nE);
    sort_kernel<<<(nE + 255) / 256, 256, 0, stream>>>(src, dst, cursor, esrc, nE);

    // layer 1
    gemm128<<<(N_NODES + 63) / 64, 256, 0, stream>>>(x, W1, A, N_NODES);
    agg_kernel<<<(N_NODES + 3) / 4, 256, 0, stream>>>(A, B, dinv, row_ptr, esrc, b1);
    // layer 2
    gemm128<<<(N_NODES + 63) / 64, 256, 0, stream>>>(B, W2, A, N_NODES);
    agg_kernel<<<(N_NODES + 3) / 4, 256, 0, stream>>>(A, B, dinv, row_ptr, esrc, b2);

    // pool + fc
    pool_kernel<<<(N_NODES + 127) / 128, 128, 0, stream>>>(B, batch, pooled, cnt);
    fc_kernel<<<(N_GRAPHS * N_CLASSES + 255) / 256, 256, 0, stream>>>(pooled, cnt, fcW, fcb, out);
}

// Round 3
// 719.716 us; speedup vs baseline: 1.2276x; 1.2276x over previous
//
#include <hip/hip_runtime.h>
#include <hip/hip_bf16.h>

#define N_NODES   100000
#define N_EDGES   1600000
#define FDIM      128
#define N_GRAPHS  64
#define N_CLASSES 32

#define SCAN_CHUNK 2048
#define SCAN_NBLK  ((N_NODES + SCAN_CHUNK - 1) / SCAN_CHUNK)   // 49

// ---------------- degree count ----------------
__global__ __launch_bounds__(256) void deg_kernel(const int* __restrict__ dst, int* __restrict__ degi, int nE) {
    int e = blockIdx.x * 256 + threadIdx.x;
    if (e < nE) atomicAdd(&degi[dst[e]], 1);
}

// ---------------- dinv = rsqrt(deg+1) ----------------
__global__ __launch_bounds__(256) void dinv_kernel(const int* __restrict__ degi, float* __restrict__ dinv) {
    int i = blockIdx.x * 256 + threadIdx.x;
    if (i < N_NODES) dinv[i] = rsqrtf((float)degi[i] + 1.0f);
}

// ---------------- two-level exclusive scan ----------------
// p1: per-block (2048-elem chunk) sum
__global__ __launch_bounds__(256) void scan_p1(const int* __restrict__ degi, int* __restrict__ blockSums) {
    __shared__ int wsum[4];
    int b = blockIdx.x, t = threadIdx.x;
    int base = b * SCAN_CHUNK;
    int sum = 0;
    #pragma unroll
    for (int j = 0; j < SCAN_CHUNK / 256; ++j) {
        int idx = base + j * 256 + t;
        sum += (idx < N_NODES) ? degi[idx] : 0;
    }
    #pragma unroll
    for (int off = 32; off; off >>= 1) sum += __shfl_down(sum, off, 64);
    int lane = t & 63, w = t >> 6;
    if (lane == 0) wsum[w] = sum;
    __syncthreads();
    if (t == 0) blockSums[b] = wsum[0] + wsum[1] + wsum[2] + wsum[3];
}

// p2: single-wave exclusive scan of the 49 block sums
__global__ __launch_bounds__(64) void scan_p2(int* __restrict__ blockSums) {
    int t = threadIdx.x;
    int v = (t < SCAN_NBLK) ? blockSums[t] : 0;
    int inc = v;
    #pragma unroll
    for (int off = 1; off < 64; off <<= 1) {
        int y = __shfl_up(inc, off, 64);
        if (t >= off) inc += y;
    }
    if (t < SCAN_NBLK) blockSums[t] = inc - v;   // exclusive
}

// p3: per-block exclusive scan + block offset -> row_ptr, cursor
__global__ __launch_bounds__(256) void scan_p3(const int* __restrict__ degi, const int* __restrict__ blockSums,
                                               int* __restrict__ row_ptr, int* __restrict__ cursor, int nE) {
    __shared__ int wsum[4];
    int b = blockIdx.x, t = threadIdx.x;
    int lane = t & 63, w = t >> 6;
    int i0 = b * SCAN_CHUNK + t * 8;
    int v[8];
    int s = 0;
    #pragma unroll
    for (int j = 0; j < 8; ++j) {
        int idx = i0 + j;
        v[j] = (idx < N_NODES) ? degi[idx] : 0;
        s += v[j];
    }
    int ps = s;   // inclusive wave scan of per-thread sums
    #pragma unroll
    for (int off = 1; off < 64; off <<= 1) {
        int y = __shfl_up(ps, off, 64);
        if (lane >= off) ps += y;
    }
    if (lane == 63) wsum[w] = ps;
    __syncthreads();
    if (t == 0) {
        int a = 0;
        #pragma unroll
        for (int i = 0; i < 4; ++i) { int tmp = wsum[i]; wsum[i] = a; a += tmp; }
    }
    __syncthreads();
    int run = (ps - s) + wsum[w] + blockSums[b];
    #pragma unroll
    for (int j = 0; j < 8; ++j) {
        int idx = i0 + j;
        if (idx < N_NODES) { row_ptr[idx] = run; cursor[idx] = run; }
        run += v[j];
    }
    if (b == 0 && t == 0) row_ptr[N_NODES] = nE;
}

// ---------------- counting-sort edges by dst ----------------
__global__ __launch_bounds__(256) void sort_kernel(const int* __restrict__ src, const int* __restrict__ dst,
                                                   int* __restrict__ cursor, int* __restrict__ esrc, int nE) {
    int e = blockIdx.x * 256 + threadIdx.x;
    if (e < nE) {
        int d = dst[e];
        int pos = atomicAdd(&cursor[d], 1);
        esrc[pos] = src[e];
    }
}

// ---------------- f32 GEMM: C[n x 128] = X[n x 128] @ W[128 x 128] ----------------
__global__ __launch_bounds__(256) void gemm128(const float* __restrict__ X, const float* __restrict__ W,
                                               float* __restrict__ C, int nrows) {
    __shared__ float xs[64 * 128];
    int t = threadIdx.x;
    long long base = (long long)blockIdx.x * 64;
    int valid = nrows - (int)base; if (valid > 64) valid = 64;
    int nelem = valid * 128;
    #pragma unroll
    for (int i = 0; i < 8; ++i) {
        int idx4 = i * 256 + t;
        int idx  = idx4 * 4;
        float4 v = make_float4(0.f, 0.f, 0.f, 0.f);
        if (idx < nelem) v = *(const float4*)(X + base * 128 + idx);
        *(float4*)(xs + idx) = v;
    }
    __syncthreads();
    int tc = t & 31;   // col group (4 cols)
    int tr = t >> 5;   // row group (8 rows)
    int c0 = tc * 4;
    float acc[8][4];
    #pragma unroll
    for (int r = 0; r < 8; ++r)
        #pragma unroll
        for (int c = 0; c < 4; ++c) acc[r][c] = 0.f;
    #pragma unroll 8
    for (int k = 0; k < 128; ++k) {
        float4 wv = *(const float4*)(W + k * 128 + c0);
        #pragma unroll
        for (int r = 0; r < 8; ++r) {
            float xv = xs[(tr * 8 + r) * 128 + k];
            acc[r][0] += xv * wv.x;
            acc[r][1] += xv * wv.y;
            acc[r][2] += xv * wv.z;
            acc[r][3] += xv * wv.w;
        }
    }
    #pragma unroll
    for (int r = 0; r < 8; ++r) {
        long long row = base + tr * 8 + r;
        if (row < nrows)
            *(float4*)(C + row * 128 + c0) = make_float4(acc[r][0], acc[r][1], acc[r][2], acc[r][3]);
    }
}

// ---------------- aggregation: O = relu( D^-1/2 (A+I) D^-1/2 H + b ) ----------------
__global__ __launch_bounds__(256) void agg_kernel(const float* __restrict__ H, float* __restrict__ O,
                                                  const float* __restrict__ dinv,
                                                  const int* __restrict__ row_ptr,
                                                  const int* __restrict__ esrc,
                                                  const float* __restrict__ bias) {
    int node = blockIdx.x * 4 + (threadIdx.x >> 6);
    if (node >= N_NODES) return;
    int lane = threadIdx.x & 63;
    float dv = dinv[node];
    float2 hv = *((const float2*)(H + (long long)node * FDIM) + lane);
    float sw = dv * dv;
    float ax = hv.x * sw, ay = hv.y * sw;
    int beg = row_ptr[node], end = row_ptr[node + 1];
    int sNext = (beg < end) ? esrc[beg] : 0;
    for (int e = beg; e < end; ++e) {
        int s = sNext;
        if (e + 1 < end) sNext = esrc[e + 1];
        float w = dinv[s] * dv;
        float2 m = *((const float2*)(H + (long long)s * FDIM) + lane);
        ax += m.x * w;
        ay += m.y * w;
    }
    float2 bb = *((const float2*)bias + lane);
    ax += bb.x; ay += bb.y;
    ax = fmaxf(ax, 0.f); ay = fmaxf(ay, 0.f);
    *((float2*)(O + (long long)node * FDIM) + lane) = make_float2(ax, ay);
}

// ---------------- pooling: per-graph feature sums + counts (batch sorted) ----------------
__global__ __launch_bounds__(128) void pool_kernel(const float* __restrict__ H, const int* __restrict__ batch,
                                                   float* __restrict__ pooled, float* __restrict__ cnt) {
    int f  = threadIdx.x;           // 0..127
    int r0 = blockIdx.x * 128;
    int rend = r0 + 128; if (rend > N_NODES) rend = N_NODES;
    if (r0 >= N_NODES) return;
    float acc = 0.f;
    int g_cur = batch[r0];
    int run = 0;
    for (int r = r0; r < rend; ++r) {
        int g = batch[r];
        if (g != g_cur) {
            atomicAdd(&pooled[g_cur * FDIM + f], acc);
            if (f == 0) atomicAdd(&cnt[g_cur], (float)run);
            acc = 0.f; run = 0; g_cur = g;
        }
        acc += H[(long long)r * FDIM + f];
        run++;
    }
    atomicAdd(&pooled[g_cur * FDIM + f], acc);
    if (f == 0) atomicAdd(&cnt[g_cur], (float)run);
}

// ---------------- final FC ----------------
__global__ __launch_bounds__(256) void fc_kernel(const float* __restrict__ pooled, const float* __restrict__ cnt,
                                                 const float* __restrict__ fcW, const float* __restrict__ fcb,
                                                 float* __restrict__ out) {
    int idx = blockIdx.x * 256 + threadIdx.x;
    if (idx >= N_GRAPHS * N_CLASSES) return;
    int g = idx >> 5, c = idx & 31;
    float inv = 1.0f / fmaxf(cnt[g], 1.0f);
    float acc = 0.f;
    #pragma unroll 16
    for (int k = 0; k < FDIM; ++k) acc += pooled[g * FDIM + k] * fcW[k * N_CLASSES + c];
    out[idx] = acc * inv + fcb[c];
}

extern "C" void kernel_launch(void* const* d_in, const int* in_sizes, int n_in,
                              void* d_out, int out_size, void* d_ws, size_t ws_size,
                              hipStream_t stream) {
    const float* x    = (const float*)d_in[0];
    const int*   ei   = (const int*)d_in[1];     // [2, E] int32
    const int*   batch= (const int*)d_in[2];
    const float* W1   = (const float*)d_in[3];
    const float* b1   = (const float*)d_in[4];
    const float* W2   = (const float*)d_in[5];
    const float* b2   = (const float*)d_in[6];
    const float* fcW  = (const float*)d_in[7];
    const float* fcb  = (const float*)d_in[8];
    float* out = (float*)d_out;

    const int nE = in_sizes[1] / 2;
    const int* src = ei;
    const int* dst = ei + nE;

    // workspace layout
    float* A       = (float*)d_ws;                       // N*F
    float* B       = A + (long long)N_NODES * FDIM;      // N*F
    float* dinv    = B + (long long)N_NODES * FDIM;      // N
    int*   degi    = (int*)(dinv + N_NODES);             // N
    int*   row_ptr = degi + N_NODES;                     // N+1
    int*   cursor  = row_ptr + N_NODES + 1;              // N
    int*   esrc    = cursor + N_NODES;                   // E
    int*   bsums   = esrc + nE;                          // SCAN_NBLK
    float* pooled  = (float*)(bsums + SCAN_NBLK);        // G*F
    float* cnt     = pooled + N_GRAPHS * FDIM;           // G

    hipMemsetAsync(degi, 0, N_NODES * sizeof(int), stream);
    hipMemsetAsync(pooled, 0, (N_GRAPHS * FDIM + N_GRAPHS) * sizeof(float), stream);

    deg_kernel<<<(nE + 255) / 256, 256, 0, stream>>>(dst, degi, nE);
    dinv_kernel<<<(N_NODES + 255) / 256, 256, 0, stream>>>(degi, dinv);
    scan_p1<<<SCAN_NBLK, 256, 0, stream>>>(degi, bsums);
    scan_p2<<<1, 64, 0, stream>>>(bsums);
    scan_p3<<<SCAN_NBLK, 256, 0, stream>>>(degi, bsums, row_ptr, cursor, nE);
    sort_kernel<<<(nE + 255) / 256, 256, 0, stream>>>(src, dst, cursor, esrc, nE);

    // layer 1
    gemm128<<<(N_NODES + 63) / 64, 256, 0, stream>>>(x, W1, A, N_NODES);
    agg_kernel<<<(N_NODES + 3) / 4, 256, 0, stream>>>(A, B, dinv, row_ptr, esrc, b1);
    // layer 2
    gemm128<<<(N_NODES + 63) / 64, 256, 0, stream>>>(B, W2, A, N_NODES);
    agg_kernel<<<(N_NODES + 3) / 4, 256, 0, stream>>>(A, B, dinv, row_ptr, esrc, b2);

    // pool + fc
    pool_kernel<<<(N_NODES + 127) / 128, 128, 0, stream>>>(B, batch, pooled, cnt);
    fc_kernel<<<(N_GRAPHS * N_CLASSES + 255) / 256, 256, 0, stream>>>(pooled, cnt, fcW, fcb, out);
}

// Round 4
// 627.609 us; speedup vs baseline: 1.4078x; 1.1468x over previous
//
#include <hip/hip_runtime.h>
#include <hip/hip_bf16.h>

#define N_NODES   100000
#define FDIM      128
#define N_GRAPHS  64
#define N_CLASSES 32

#define SCAN_CHUNK 2048
#define SCAN_NBLK  ((N_NODES + SCAN_CHUNK - 1) / SCAN_CHUNK)   // 49

typedef __attribute__((ext_vector_type(8))) short short8;
typedef __attribute__((ext_vector_type(4))) float f32x4;

__device__ __forceinline__ float bf2f(unsigned int u16) {
    unsigned int x = u16 << 16;
    return __builtin_bit_cast(float, x);
}
__device__ __forceinline__ unsigned short f2bf(float f) {
    unsigned int u = __builtin_bit_cast(unsigned int, f);
    unsigned int r = (u + 0x7fffu + ((u >> 16) & 1u)) >> 16;   // RNE
    return (unsigned short)r;
}

// ---------------- degree count ----------------
__global__ __launch_bounds__(256) void deg_kernel(const int* __restrict__ dst, int* __restrict__ degi, int nE) {
    int e = blockIdx.x * 256 + threadIdx.x;
    if (e < nE) atomicAdd(&degi[dst[e]], 1);
}

// ---------------- dinv = rsqrt(deg+1) ----------------
__global__ __launch_bounds__(256) void dinv_kernel(const int* __restrict__ degi, float* __restrict__ dinv) {
    int i = blockIdx.x * 256 + threadIdx.x;
    if (i < N_NODES) dinv[i] = rsqrtf((float)degi[i] + 1.0f);
}

// ---------------- two-level exclusive scan ----------------
__global__ __launch_bounds__(256) void scan_p1(const int* __restrict__ degi, int* __restrict__ blockSums) {
    __shared__ int wsum[4];
    int b = blockIdx.x, t = threadIdx.x;
    int base = b * SCAN_CHUNK;
    int sum = 0;
    #pragma unroll
    for (int j = 0; j < SCAN_CHUNK / 256; ++j) {
        int idx = base + j * 256 + t;
        sum += (idx < N_NODES) ? degi[idx] : 0;
    }
    #pragma unroll
    for (int off = 32; off; off >>= 1) sum += __shfl_down(sum, off, 64);
    int lane = t & 63, w = t >> 6;
    if (lane == 0) wsum[w] = sum;
    __syncthreads();
    if (t == 0) blockSums[b] = wsum[0] + wsum[1] + wsum[2] + wsum[3];
}

__global__ __launch_bounds__(64) void scan_p2(int* __restrict__ blockSums) {
    int t = threadIdx.x;
    int v = (t < SCAN_NBLK) ? blockSums[t] : 0;
    int inc = v;
    #pragma unroll
    for (int off = 1; off < 64; off <<= 1) {
        int y = __shfl_up(inc, off, 64);
        if (t >= off) inc += y;
    }
    if (t < SCAN_NBLK) blockSums[t] = inc - v;   // exclusive
}

__global__ __launch_bounds__(256) void scan_p3(const int* __restrict__ degi, const int* __restrict__ blockSums,
                                               int* __restrict__ row_ptr, int* __restrict__ cursor, int nE) {
    __shared__ int wsum[4];
    int b = blockIdx.x, t = threadIdx.x;
    int lane = t & 63, w = t >> 6;
    int i0 = b * SCAN_CHUNK + t * 8;
    int v[8];
    int s = 0;
    #pragma unroll
    for (int j = 0; j < 8; ++j) {
        int idx = i0 + j;
        v[j] = (idx < N_NODES) ? degi[idx] : 0;
        s += v[j];
    }
    int ps = s;
    #pragma unroll
    for (int off = 1; off < 64; off <<= 1) {
        int y = __shfl_up(ps, off, 64);
        if (lane >= off) ps += y;
    }
    if (lane == 63) wsum[w] = ps;
    __syncthreads();
    if (t == 0) {
        int a = 0;
        #pragma unroll
        for (int i = 0; i < 4; ++i) { int tmp = wsum[i]; wsum[i] = a; a += tmp; }
    }
    __syncthreads();
    int run = (ps - s) + wsum[w] + blockSums[b];
    #pragma unroll
    for (int j = 0; j < 8; ++j) {
        int idx = i0 + j;
        if (idx < N_NODES) { row_ptr[idx] = run; cursor[idx] = run; }
        run += v[j];
    }
    if (b == 0 && t == 0) row_ptr[N_NODES] = nE;
}

// ---------------- counting-sort edges by dst ----------------
__global__ __launch_bounds__(256) void sort_kernel(const int* __restrict__ src, const int* __restrict__ dst,
                                                   int* __restrict__ cursor, int* __restrict__ esrc, int nE) {
    int e = blockIdx.x * 256 + threadIdx.x;
    if (e < nE) {
        int d = dst[e];
        int pos = atomicAdd(&cursor[d], 1);
        esrc[pos] = src[e];
    }
}

// ---------------- W transpose + cast: WT[n][k] bf16 from W[k][n] f32 ----------------
__global__ __launch_bounds__(256) void wtrans(const float* __restrict__ W, unsigned short* __restrict__ WT) {
    int t = threadIdx.x;
    #pragma unroll
    for (int j = 0; j < 64; ++j) {
        int idx = j * 256 + t;
        int k = idx >> 7, n = idx & 127;
        WT[n * 128 + k] = f2bf(W[idx]);
    }
}

// ---------------- MFMA GEMM: H[nrows x 128](bf16) = X[nrows x 128] @ W[128 x 128] ----------------
// X is f32 (IN_F32=1) or bf16 (IN_F32=0); WT is bf16 [n][k].
// 128x128 tile, 4 waves; wave w: rows [32w,32w+32) x 128 cols.
// LDS XOR-swizzle (byte ^= (row&7)<<4) -> 2-way bank aliasing (free) on ds_read_b128.
template<int IN_F32>
__global__ __launch_bounds__(256) void gemm_mfma(const void* __restrict__ Xv,
                                                 const unsigned short* __restrict__ WT,
                                                 unsigned short* __restrict__ H, int nrows) {
    __shared__ char lds[65536];
    char* xs  = lds;            // 128x128 bf16, swizzled
    char* wsh = lds + 32768;    // WT 128x128 bf16 ([n][k]), swizzled
    int t = threadIdx.x;
    int base = blockIdx.x * 128;

    // stage WT
    #pragma unroll
    for (int j = 0; j < 8; ++j) {
        int idx = j * 256 + t;
        int n = idx >> 4, c8 = idx & 15;
        short8 v = *(const short8*)(WT + n * 128 + c8 * 8);
        int off = (n * 256 + c8 * 16) ^ ((n & 7) << 4);
        *(short8*)(wsh + off) = v;
    }
    // stage X
    #pragma unroll
    for (int j = 0; j < 8; ++j) {
        int idx = j * 256 + t;
        int row = idx >> 4, c8 = idx & 15;
        int grow = base + row;
        short8 v = {0,0,0,0,0,0,0,0};
        if (grow < nrows) {
            if (IN_F32) {
                const float* Xf = (const float*)Xv;
                float4 a = *(const float4*)(Xf + (size_t)grow * 128 + c8 * 8);
                float4 b = *(const float4*)(Xf + (size_t)grow * 128 + c8 * 8 + 4);
                v[0] = (short)f2bf(a.x); v[1] = (short)f2bf(a.y);
                v[2] = (short)f2bf(a.z); v[3] = (short)f2bf(a.w);
                v[4] = (short)f2bf(b.x); v[5] = (short)f2bf(b.y);
                v[6] = (short)f2bf(b.z); v[7] = (short)f2bf(b.w);
            } else {
                const unsigned short* Xb = (const unsigned short*)Xv;
                v = *(const short8*)(Xb + (size_t)grow * 128 + c8 * 8);
            }
        }
        int off = (row * 256 + c8 * 16) ^ ((row & 7) << 4);
        *(short8*)(xs + off) = v;
    }
    __syncthreads();

    int lane = t & 63, w = t >> 6;
    int lhi = lane >> 4, llo = lane & 15;
    f32x4 acc[2][8];
    #pragma unroll
    for (int r = 0; r < 2; ++r)
        #pragma unroll
        for (int c = 0; c < 8; ++c) acc[r][c] = (f32x4){0.f, 0.f, 0.f, 0.f};

    #pragma unroll
    for (int kk = 0; kk < 4; ++kk) {
        short8 a[2];
        #pragma unroll
        for (int r = 0; r < 2; ++r) {
            int row = w * 32 + r * 16 + llo;                      // A: row = lane&15
            int off = (row * 256 + kk * 64 + lhi * 16) ^ ((row & 7) << 4);
            a[r] = *(const short8*)(xs + off);
        }
        #pragma unroll
        for (int c = 0; c < 8; ++c) {
            int col = c * 16 + llo;                               // B: col = lane&15
            int off = (col * 256 + kk * 64 + lhi * 16) ^ ((col & 7) << 4);
            short8 b = *(const short8*)(wsh + off);
            acc[0][c] = __builtin_amdgcn_mfma_f32_16x16x32_bf16(a[0], b, acc[0][c], 0, 0, 0);
            acc[1][c] = __builtin_amdgcn_mfma_f32_16x16x32_bf16(a[1], b, acc[1][c], 0, 0, 0);
        }
    }

    // D: col = lane&15, row = (lane>>4)*4 + reg
    #pragma unroll
    for (int r = 0; r < 2; ++r) {
        #pragma unroll
        for (int reg = 0; reg < 4; ++reg) {
            int grow = base + w * 32 + r * 16 + lhi * 4 + reg;
            if (grow < nrows) {
                #pragma unroll
                for (int c = 0; c < 8; ++c)
                    H[(size_t)grow * 128 + c * 16 + llo] = f2bf(acc[r][c][reg]);
            }
        }
    }
}

// ---------------- aggregation (bf16 features): O = relu(D^-1/2 (A+I) D^-1/2 H + b) ----------------
__global__ __launch_bounds__(256) void agg_bf16(const unsigned int* __restrict__ H, unsigned int* __restrict__ O,
                                                const float* __restrict__ dinv,
                                                const int* __restrict__ row_ptr,
                                                const int* __restrict__ esrc,
                                                const float* __restrict__ bias) {
    int node = blockIdx.x * 4 + (threadIdx.x >> 6);
    if (node >= N_NODES) return;
    int lane = threadIdx.x & 63;
    float dv = dinv[node];
    unsigned int pv = H[(size_t)node * 64 + lane];
    float sw = dv * dv;
    float ax = bf2f(pv & 0xffffu) * sw;
    float ay = bf2f(pv >> 16) * sw;
    int beg = row_ptr[node], end = row_ptr[node + 1];
    int sNext = (beg < end) ? esrc[beg] : 0;
    for (int e = beg; e < end; ++e) {
        int s = sNext;
        if (e + 1 < end) sNext = esrc[e + 1];
        float wgt = dinv[s] * dv;
        unsigned int mv = H[(size_t)s * 64 + lane];
        ax += bf2f(mv & 0xffffu) * wgt;
        ay += bf2f(mv >> 16) * wgt;
    }
    float2 bb = ((const float2*)bias)[lane];
    ax = fmaxf(ax + bb.x, 0.f);
    ay = fmaxf(ay + bb.y, 0.f);
    O[(size_t)node * 64 + lane] = (unsigned int)f2bf(ax) | ((unsigned int)f2bf(ay) << 16);
}

// ---------------- pooling (bf16 input): per-graph sums + counts (batch sorted) ----------------
__global__ __launch_bounds__(128) void pool_kernel(const unsigned short* __restrict__ H, const int* __restrict__ batch,
                                                   float* __restrict__ pooled, float* __restrict__ cnt) {
    int f  = threadIdx.x;           // 0..127
    int r0 = blockIdx.x * 128;
    int rend = r0 + 128; if (rend > N_NODES) rend = N_NODES;
    if (r0 >= N_NODES) return;
    float acc = 0.f;
    int g_cur = batch[r0];
    int run = 0;
    for (int r = r0; r < rend; ++r) {
        int g = batch[r];
        if (g != g_cur) {
            atomicAdd(&pooled[g_cur * FDIM + f], acc);
            if (f == 0) atomicAdd(&cnt[g_cur], (float)run);
            acc = 0.f; run = 0; g_cur = g;
        }
        acc += bf2f(H[(size_t)r * FDIM + f]);
        run++;
    }
    atomicAdd(&pooled[g_cur * FDIM + f], acc);
    if (f == 0) atomicAdd(&cnt[g_cur], (float)run);
}

// ---------------- final FC ----------------
__global__ __launch_bounds__(256) void fc_kernel(const float* __restrict__ pooled, const float* __restrict__ cnt,
                                                 const float* __restrict__ fcW, const float* __restrict__ fcb,
                                                 float* __restrict__ out) {
    int idx = blockIdx.x * 256 + threadIdx.x;
    if (idx >= N_GRAPHS * N_CLASSES) return;
    int g = idx >> 5, c = idx & 31;
    float inv = 1.0f / fmaxf(cnt[g], 1.0f);
    float acc = 0.f;
    #pragma unroll 16
    for (int k = 0; k < FDIM; ++k) acc += pooled[g * FDIM + k] * fcW[k * N_CLASSES + c];
    out[idx] = acc * inv + fcb[c];
}

extern "C" void kernel_launch(void* const* d_in, const int* in_sizes, int n_in,
                              void* d_out, int out_size, void* d_ws, size_t ws_size,
                              hipStream_t stream) {
    const float* x    = (const float*)d_in[0];
    const int*   ei   = (const int*)d_in[1];     // [2, E] int32
    const int*   batch= (const int*)d_in[2];
    const float* W1   = (const float*)d_in[3];
    const float* b1   = (const float*)d_in[4];
    const float* W2   = (const float*)d_in[5];
    const float* b2   = (const float*)d_in[6];
    const float* fcW  = (const float*)d_in[7];
    const float* fcb  = (const float*)d_in[8];
    float* out = (float*)d_out;

    const int nE = in_sizes[1] / 2;
    const int* src = ei;
    const int* dst = ei + nE;

    // workspace layout
    unsigned short* Hb0 = (unsigned short*)d_ws;                 // N*128 bf16
    unsigned short* Hb1 = Hb0 + (size_t)N_NODES * FDIM;          // N*128 bf16
    unsigned short* W1T = Hb1 + (size_t)N_NODES * FDIM;          // 128*128 bf16
    unsigned short* W2T = W1T + FDIM * FDIM;                     // 128*128 bf16
    float* dinv    = (float*)(W2T + FDIM * FDIM);                // N
    int*   degi    = (int*)(dinv + N_NODES);                     // N
    int*   row_ptr = degi + N_NODES;                             // N+1
    int*   cursor  = row_ptr + N_NODES + 1;                      // N
    int*   esrc    = cursor + N_NODES;                           // E
    int*   bsums   = esrc + nE;                                  // SCAN_NBLK
    float* pooled  = (float*)(bsums + SCAN_NBLK);                // G*F
    float* cnt     = pooled + N_GRAPHS * FDIM;                   // G

    hipMemsetAsync(degi, 0, N_NODES * sizeof(int), stream);
    hipMemsetAsync(pooled, 0, (N_GRAPHS * FDIM + N_GRAPHS) * sizeof(float), stream);

    deg_kernel<<<(nE + 255) / 256, 256, 0, stream>>>(dst, degi, nE);
    dinv_kernel<<<(N_NODES + 255) / 256, 256, 0, stream>>>(degi, dinv);
    scan_p1<<<SCAN_NBLK, 256, 0, stream>>>(degi, bsums);
    scan_p2<<<1, 64, 0, stream>>>(bsums);
    scan_p3<<<SCAN_NBLK, 256, 0, stream>>>(degi, bsums, row_ptr, cursor, nE);
    sort_kernel<<<(nE + 255) / 256, 256, 0, stream>>>(src, dst, cursor, esrc, nE);

    wtrans<<<1, 256, 0, stream>>>(W1, W1T);
    wtrans<<<1, 256, 0, stream>>>(W2, W2T);

    const int gemm_grid = (N_NODES + 127) / 128;
    // layer 1
    gemm_mfma<1><<<gemm_grid, 256, 0, stream>>>(x, W1T, Hb0, N_NODES);
    agg_bf16<<<(N_NODES + 3) / 4, 256, 0, stream>>>((const unsigned int*)Hb0, (unsigned int*)Hb1,
                                                     dinv, row_ptr, esrc, b1);
    // layer 2
    gemm_mfma<0><<<gemm_grid, 256, 0, stream>>>(Hb1, W2T, Hb0, N_NODES);
    agg_bf16<<<(N_NODES + 3) / 4, 256, 0, stream>>>((const unsigned int*)Hb0, (unsigned int*)Hb1,
                                                     dinv, row_ptr, esrc, b2);

    // pool + fc
    pool_kernel<<<(N_NODES + 127) / 128, 128, 0, stream>>>(Hb1, batch, pooled, cnt);
    fc_kernel<<<(N_GRAPHS * N_CLASSES + 255) / 256, 256, 0, stream>>>(pooled, cnt, fcW, fcb, out);
}

// Round 5
// 450.389 us; speedup vs baseline: 1.9617x; 1.3935x over previous
//
#include <hip/hip_runtime.h>
#include <hip/hip_bf16.h>

#define N_NODES   100000
#define FDIM      128
#define N_GRAPHS  64
#define N_CLASSES 32

#define NB        ((N_NODES + 255) / 256)     // 391 buckets of 256 nodes
#define EPB       8192                         // edges per block (hist/part)
#define SCAN_CHUNK 2048

typedef __attribute__((ext_vector_type(8))) short short8;
typedef __attribute__((ext_vector_type(4))) float f32x4;

__device__ __forceinline__ float bf2f(unsigned int u16) {
    unsigned int x = u16 << 16;
    return __builtin_bit_cast(float, x);
}
__device__ __forceinline__ unsigned short f2bf(float f) {
    unsigned int u = __builtin_bit_cast(unsigned int, f);
    unsigned int r = (u + 0x7fffu + ((u >> 16) & 1u)) >> 16;   // RNE
    return (unsigned short)r;
}

// ---------------- bucket histogram: hist[bucket * nblk + blk] ----------------
__global__ __launch_bounds__(256) void hist_kernel(const int* __restrict__ dst, int* __restrict__ hist,
                                                   int nE, int nblk) {
    __shared__ int h[NB];
    int t = threadIdx.x, blk = blockIdx.x;
    for (int i = t; i < NB; i += 256) h[i] = 0;
    __syncthreads();
    int base = blk * EPB;
    #pragma unroll
    for (int j = 0; j < EPB / 256; ++j) {
        int e = base + j * 256 + t;
        if (e < nE) atomicAdd(&h[dst[e] >> 8], 1);
    }
    __syncthreads();
    for (int i = t; i < NB; i += 256) hist[i * nblk + blk] = h[i];
}

// ---------------- generic two-level exclusive scan ----------------
__global__ __launch_bounds__(256) void scan_p1(const int* __restrict__ a, int* __restrict__ bsums, int n) {
    __shared__ int wsum[4];
    int b = blockIdx.x, t = threadIdx.x;
    int base = b * SCAN_CHUNK;
    int sum = 0;
    #pragma unroll
    for (int j = 0; j < SCAN_CHUNK / 256; ++j) {
        int idx = base + j * 256 + t;
        sum += (idx < n) ? a[idx] : 0;
    }
    #pragma unroll
    for (int off = 32; off; off >>= 1) sum += __shfl_down(sum, off, 64);
    int lane = t & 63, w = t >> 6;
    if (lane == 0) wsum[w] = sum;
    __syncthreads();
    if (t == 0) bsums[b] = wsum[0] + wsum[1] + wsum[2] + wsum[3];
}

__global__ __launch_bounds__(64) void scan_p2(int* __restrict__ bsums, int nb) {
    int t = threadIdx.x;
    int carry = 0;
    for (int base = 0; base < nb; base += 64) {
        int i = base + t;
        int v = (i < nb) ? bsums[i] : 0;
        int inc = v;
        #pragma unroll
        for (int off = 1; off < 64; off <<= 1) {
            int y = __shfl_up(inc, off, 64);
            if (t >= off) inc += y;
        }
        if (i < nb) bsums[i] = carry + inc - v;   // exclusive
        carry += __shfl(inc, 63, 64);
    }
}

__global__ __launch_bounds__(256) void scan_p3(const int* __restrict__ a, const int* __restrict__ bsums,
                                               int* __restrict__ out, int n) {
    __shared__ int wsum[4];
    int b = blockIdx.x, t = threadIdx.x;
    int lane = t & 63, w = t >> 6;
    int i0 = b * SCAN_CHUNK + t * 8;
    int v[8];
    int s = 0;
    #pragma unroll
    for (int j = 0; j < 8; ++j) {
        int idx = i0 + j;
        v[j] = (idx < n) ? a[idx] : 0;
        s += v[j];
    }
    int ps = s;
    #pragma unroll
    for (int off = 1; off < 64; off <<= 1) {
        int y = __shfl_up(ps, off, 64);
        if (lane >= off) ps += y;
    }
    if (lane == 63) wsum[w] = ps;
    __syncthreads();
    if (t == 0) {
        int acc = 0;
        #pragma unroll
        for (int i = 0; i < 4; ++i) { int tmp = wsum[i]; wsum[i] = acc; acc += tmp; }
    }
    __syncthreads();
    int run = (ps - s) + wsum[w] + bsums[b];
    #pragma unroll
    for (int j = 0; j < 8; ++j) {
        int idx = i0 + j;
        if (idx < n) out[idx] = run;
        run += v[j];
    }
}

// ---------------- partition edges into bucket-major record array ----------------
__global__ __launch_bounds__(256) void part_kernel(const int* __restrict__ src, const int* __restrict__ dst,
                                                   const int* __restrict__ offs,
                                                   unsigned long long* __restrict__ recs,
                                                   int nE, int nblk) {
    __shared__ int cur[NB];
    int t = threadIdx.x, blk = blockIdx.x;
    for (int i = t; i < NB; i += 256) cur[i] = offs[i * nblk + blk];
    __syncthreads();
    int base = blk * EPB;
    #pragma unroll
    for (int j = 0; j < EPB / 256; ++j) {
        int e = base + j * 256 + t;
        if (e < nE) {
            int s = src[e], d = dst[e];
            int pos = atomicAdd(&cur[d >> 8], 1);
            recs[pos] = (unsigned long long)(unsigned)s | ((unsigned long long)(unsigned)d << 32);
        }
    }
}

// ---------------- per-bucket CSR build: row_ptr, esrc, dinv (fused) ----------------
__global__ __launch_bounds__(256) void csr_kernel(const unsigned long long* __restrict__ recs,
                                                  const int* __restrict__ offs,
                                                  int* __restrict__ row_ptr, int* __restrict__ esrc,
                                                  float* __restrict__ dinv, int nE, int nblk) {
    __shared__ int cnt[256];
    __shared__ int cur[256];
    __shared__ int wsum[4];
    int b = blockIdx.x, t = threadIdx.x;
    int node0 = b << 8;
    int segBeg = offs[b * nblk];
    int segEnd = (b + 1 < NB) ? offs[(b + 1) * nblk] : nE;
    cnt[t] = 0;
    __syncthreads();
    for (int e = segBeg + t; e < segEnd; e += 256) {
        int d = (int)(recs[e] >> 32);
        atomicAdd(&cnt[d - node0], 1);
    }
    __syncthreads();
    int c = cnt[t];
    int lane = t & 63, w = t >> 6;
    int ps = c;
    #pragma unroll
    for (int off = 1; off < 64; off <<= 1) {
        int y = __shfl_up(ps, off, 64);
        if (lane >= off) ps += y;
    }
    if (lane == 63) wsum[w] = ps;
    __syncthreads();
    if (t == 0) {
        int a = 0;
        #pragma unroll
        for (int i = 0; i < 4; ++i) { int tmp = wsum[i]; wsum[i] = a; a += tmp; }
    }
    __syncthreads();
    int gbase = segBeg + (ps - c) + wsum[w];
    cur[t] = gbase;
    int node = node0 + t;
    if (node < N_NODES) {
        row_ptr[node] = gbase;
        dinv[node] = rsqrtf((float)c + 1.0f);
    }
    if (b == NB - 1 && t == 0) row_ptr[N_NODES] = nE;
    __syncthreads();
    for (int e = segBeg + t; e < segEnd; e += 256) {
        unsigned long long r = recs[e];
        int d = (int)(r >> 32);
        int pos = atomicAdd(&cur[d - node0], 1);
        esrc[pos] = (int)(r & 0xffffffffu);
    }
}

// ---------------- W transpose + cast: WT[n][k] bf16 from W[k][n] f32 ----------------
__global__ __launch_bounds__(256) void wtrans(const float* __restrict__ W, unsigned short* __restrict__ WT) {
    int idx = blockIdx.x * 256 + threadIdx.x;
    int k = idx >> 7, n = idx & 127;
    WT[n * 128 + k] = f2bf(W[idx]);
}

// ---------------- MFMA GEMM: H[nrows x 128](bf16) = X[nrows x 128] @ W[128 x 128] ----------------
template<int IN_F32>
__global__ __launch_bounds__(256) void gemm_mfma(const void* __restrict__ Xv,
                                                 const unsigned short* __restrict__ WT,
                                                 unsigned short* __restrict__ H, int nrows) {
    __shared__ char lds[65536];
    char* xs  = lds;            // 128x128 bf16, swizzled
    char* wsh = lds + 32768;    // WT 128x128 bf16 ([n][k]), swizzled
    int t = threadIdx.x;
    int base = blockIdx.x * 128;

    #pragma unroll
    for (int j = 0; j < 8; ++j) {
        int idx = j * 256 + t;
        int n = idx >> 4, c8 = idx & 15;
        short8 v = *(const short8*)(WT + n * 128 + c8 * 8);
        int off = (n * 256 + c8 * 16) ^ ((n & 7) << 4);
        *(short8*)(wsh + off) = v;
    }
    #pragma unroll
    for (int j = 0; j < 8; ++j) {
        int idx = j * 256 + t;
        int row = idx >> 4, c8 = idx & 15;
        int grow = base + row;
        short8 v = {0,0,0,0,0,0,0,0};
        if (grow < nrows) {
            if (IN_F32) {
                const float* Xf = (const float*)Xv;
                float4 a = *(const float4*)(Xf + (size_t)grow * 128 + c8 * 8);
                float4 b = *(const float4*)(Xf + (size_t)grow * 128 + c8 * 8 + 4);
                v[0] = (short)f2bf(a.x); v[1] = (short)f2bf(a.y);
                v[2] = (short)f2bf(a.z); v[3] = (short)f2bf(a.w);
                v[4] = (short)f2bf(b.x); v[5] = (short)f2bf(b.y);
                v[6] = (short)f2bf(b.z); v[7] = (short)f2bf(b.w);
            } else {
                const unsigned short* Xb = (const unsigned short*)Xv;
                v = *(const short8*)(Xb + (size_t)grow * 128 + c8 * 8);
            }
        }
        int off = (row * 256 + c8 * 16) ^ ((row & 7) << 4);
        *(short8*)(xs + off) = v;
    }
    __syncthreads();

    int lane = t & 63, w = t >> 6;
    int lhi = lane >> 4, llo = lane & 15;
    f32x4 acc[2][8];
    #pragma unroll
    for (int r = 0; r < 2; ++r)
        #pragma unroll
        for (int c = 0; c < 8; ++c) acc[r][c] = (f32x4){0.f, 0.f, 0.f, 0.f};

    #pragma unroll
    for (int kk = 0; kk < 4; ++kk) {
        short8 a[2];
        #pragma unroll
        for (int r = 0; r < 2; ++r) {
            int row = w * 32 + r * 16 + llo;
            int off = (row * 256 + kk * 64 + lhi * 16) ^ ((row & 7) << 4);
            a[r] = *(const short8*)(xs + off);
        }
        #pragma unroll
        for (int c = 0; c < 8; ++c) {
            int col = c * 16 + llo;
            int off = (col * 256 + kk * 64 + lhi * 16) ^ ((col & 7) << 4);
            short8 bb = *(const short8*)(wsh + off);
            acc[0][c] = __builtin_amdgcn_mfma_f32_16x16x32_bf16(a[0], bb, acc[0][c], 0, 0, 0);
            acc[1][c] = __builtin_amdgcn_mfma_f32_16x16x32_bf16(a[1], bb, acc[1][c], 0, 0, 0);
        }
    }

    #pragma unroll
    for (int r = 0; r < 2; ++r) {
        #pragma unroll
        for (int reg = 0; reg < 4; ++reg) {
            int grow = base + w * 32 + r * 16 + lhi * 4 + reg;
            if (grow < nrows) {
                #pragma unroll
                for (int c = 0; c < 8; ++c)
                    H[(size_t)grow * 128 + c * 16 + llo] = f2bf(acc[r][c][reg]);
            }
        }
    }
}

// ---------------- aggregation (bf16): O = relu(D^-1/2 (A+I) D^-1/2 H + b) ----------------
__global__ __launch_bounds__(256) void agg_bf16(const unsigned int* __restrict__ H, unsigned int* __restrict__ O,
                                                const float* __restrict__ dinv,
                                                const int* __restrict__ row_ptr,
                                                const int* __restrict__ esrc,
                                                const float* __restrict__ bias) {
    int node = blockIdx.x * 4 + (threadIdx.x >> 6);
    if (node >= N_NODES) return;
    int lane = threadIdx.x & 63;
    float dv = dinv[node];
    unsigned int pv = H[(size_t)node * 64 + lane];
    float sw = dv * dv;
    float ax = bf2f(pv & 0xffffu) * sw;
    float ay = bf2f(pv >> 16) * sw;
    int beg = row_ptr[node], end = row_ptr[node + 1];
    int sNext = (beg < end) ? esrc[beg] : 0;
    for (int e = beg; e < end; ++e) {
        int s = sNext;
        if (e + 1 < end) sNext = esrc[e + 1];
        float wgt = dinv[s] * dv;
        unsigned int mv = H[(size_t)s * 64 + lane];
        ax += bf2f(mv & 0xffffu) * wgt;
        ay += bf2f(mv >> 16) * wgt;
    }
    float2 bb = ((const float2*)bias)[lane];
    ax = fmaxf(ax + bb.x, 0.f);
    ay = fmaxf(ay + bb.y, 0.f);
    O[(size_t)node * 64 + lane] = (unsigned int)f2bf(ax) | ((unsigned int)f2bf(ay) << 16);
}

// ---------------- pooling (bf16 input) ----------------
__global__ __launch_bounds__(128) void pool_kernel(const unsigned short* __restrict__ H, const int* __restrict__ batch,
                                                   float* __restrict__ pooled, float* __restrict__ cnt) {
    int f  = threadIdx.x;
    int r0 = blockIdx.x * 128;
    int rend = r0 + 128; if (rend > N_NODES) rend = N_NODES;
    if (r0 >= N_NODES) return;
    float acc = 0.f;
    int g_cur = batch[r0];
    int run = 0;
    for (int r = r0; r < rend; ++r) {
        int g = batch[r];
        if (g != g_cur) {
            atomicAdd(&pooled[g_cur * FDIM + f], acc);
            if (f == 0) atomicAdd(&cnt[g_cur], (float)run);
            acc = 0.f; run = 0; g_cur = g;
        }
        acc += bf2f(H[(size_t)r * FDIM + f]);
        run++;
    }
    atomicAdd(&pooled[g_cur * FDIM + f], acc);
    if (f == 0) atomicAdd(&cnt[g_cur], (float)run);
}

// ---------------- final FC ----------------
__global__ __launch_bounds__(256) void fc_kernel(const float* __restrict__ pooled, const float* __restrict__ cnt,
                                                 const float* __restrict__ fcW, const float* __restrict__ fcb,
                                                 float* __restrict__ out) {
    int idx = blockIdx.x * 256 + threadIdx.x;
    if (idx >= N_GRAPHS * N_CLASSES) return;
    int g = idx >> 5, c = idx & 31;
    float inv = 1.0f / fmaxf(cnt[g], 1.0f);
    float acc = 0.f;
    #pragma unroll 16
    for (int k = 0; k < FDIM; ++k) acc += pooled[g * FDIM + k] * fcW[k * N_CLASSES + c];
    out[idx] = acc * inv + fcb[c];
}

extern "C" void kernel_launch(void* const* d_in, const int* in_sizes, int n_in,
                              void* d_out, int out_size, void* d_ws, size_t ws_size,
                              hipStream_t stream) {
    const float* x    = (const float*)d_in[0];
    const int*   ei   = (const int*)d_in[1];     // [2, E] int32
    const int*   batch= (const int*)d_in[2];
    const float* W1   = (const float*)d_in[3];
    const float* b1   = (const float*)d_in[4];
    const float* W2   = (const float*)d_in[5];
    const float* b2   = (const float*)d_in[6];
    const float* fcW  = (const float*)d_in[7];
    const float* fcb  = (const float*)d_in[8];
    float* out = (float*)d_out;

    const int nE = in_sizes[1] / 2;
    const int* src = ei;
    const int* dst = ei + nE;

    const int nblk  = (nE + EPB - 1) / EPB;           // partition blocks
    const int histN = NB * nblk;                      // histogram entries
    const int sB    = (histN + SCAN_CHUNK - 1) / SCAN_CHUNK;

    // workspace layout
    unsigned short* Hb0 = (unsigned short*)d_ws;                 // N*128 bf16
    unsigned short* Hb1 = Hb0 + (size_t)N_NODES * FDIM;          // N*128 bf16
    unsigned short* W1T = Hb1 + (size_t)N_NODES * FDIM;          // 128*128 bf16
    unsigned short* W2T = W1T + FDIM * FDIM;                     // 128*128 bf16
    float* dinv    = (float*)(W2T + FDIM * FDIM);                // N
    int*   row_ptr = (int*)(dinv + N_NODES);                     // N+1
    int*   esrc    = row_ptr + N_NODES + 1;                      // E
    unsigned long long* recs = (unsigned long long*)(esrc + ((nE + 1) & ~1)); // E (8B aligned)
    int*   hist    = (int*)(recs + nE);                          // NB*nblk (scanned in-place)
    int*   bsums   = hist + histN;                               // sB
    float* pooled  = (float*)(bsums + ((sB + 1) & ~1));          // G*F
    float* cnt     = pooled + N_GRAPHS * FDIM;                   // G

    hipMemsetAsync(pooled, 0, (N_GRAPHS * FDIM + N_GRAPHS) * sizeof(float), stream);

    wtrans<<<64, 256, 0, stream>>>(W1, W1T);
    wtrans<<<64, 256, 0, stream>>>(W2, W2T);

    // CSR build: hist -> scan -> partition -> per-bucket CSR (+dinv)
    hist_kernel<<<nblk, 256, 0, stream>>>(dst, hist, nE, nblk);
    scan_p1<<<sB, 256, 0, stream>>>(hist, bsums, histN);
    scan_p2<<<1, 64, 0, stream>>>(bsums, sB);
    scan_p3<<<sB, 256, 0, stream>>>(hist, bsums, hist, histN);   // in-place exclusive scan
    part_kernel<<<nblk, 256, 0, stream>>>(src, dst, hist, recs, nE, nblk);
    csr_kernel<<<NB, 256, 0, stream>>>(recs, hist, row_ptr, esrc, dinv, nE, nblk);

    const int gemm_grid = (N_NODES + 127) / 128;
    // layer 1
    gemm_mfma<1><<<gemm_grid, 256, 0, stream>>>(x, W1T, Hb0, N_NODES);
    agg_bf16<<<(N_NODES + 3) / 4, 256, 0, stream>>>((const unsigned int*)Hb0, (unsigned int*)Hb1,
                                                     dinv, row_ptr, esrc, b1);
    // layer 2
    gemm_mfma<0><<<gemm_grid, 256, 0, stream>>>(Hb1, W2T, Hb0, N_NODES);
    agg_bf16<<<(N_NODES + 3) / 4, 256, 0, stream>>>((const unsigned int*)Hb0, (unsigned int*)Hb1,
                                                     dinv, row_ptr, esrc, b2);

    // pool + fc
    pool_kernel<<<(N_NODES + 127) / 128, 128, 0, stream>>>(Hb1, batch, pooled, cnt);
    fc_kernel<<<(N_GRAPHS * N_CLASSES + 255) / 256, 256, 0, stream>>>(pooled, cnt, fcW, fcb, out);
}

// Round 6
// 404.174 us; speedup vs baseline: 2.1860x; 1.1143x over previous
//
#include <hip/hip_runtime.h>
#include <hip/hip_bf16.h>

#define N_NODES   100000
#define FDIM      128
#define N_GRAPHS  64
#define N_CLASSES 32

#define NB        ((N_NODES + 255) / 256)     // 391 buckets of 256 nodes
#define EPB       8192                         // edges per block (hist/part)
#define SCAN_CHUNK 2048

typedef __attribute__((ext_vector_type(8))) short short8;
typedef __attribute__((ext_vector_type(4))) float f32x4;

__device__ __forceinline__ float bf2f(unsigned int u16) {
    unsigned int x = u16 << 16;
    return __builtin_bit_cast(float, x);
}
__device__ __forceinline__ unsigned short f2bf(float f) {
    unsigned int u = __builtin_bit_cast(unsigned int, f);
    unsigned int r = (u + 0x7fffu + ((u >> 16) & 1u)) >> 16;   // RNE
    return (unsigned short)r;
}

// ---------------- bucket histogram: hist[bucket * nblk + blk] ----------------
__global__ __launch_bounds__(256) void hist_kernel(const int* __restrict__ dst, int* __restrict__ hist,
                                                   int nE, int nblk) {
    __shared__ int h[NB];
    int t = threadIdx.x, blk = blockIdx.x;
    for (int i = t; i < NB; i += 256) h[i] = 0;
    __syncthreads();
    int base = blk * EPB;
    #pragma unroll
    for (int j = 0; j < EPB / 256; ++j) {
        int e = base + j * 256 + t;
        if (e < nE) atomicAdd(&h[dst[e] >> 8], 1);
    }
    __syncthreads();
    for (int i = t; i < NB; i += 256) hist[i * nblk + blk] = h[i];
}

// ---------------- generic two-level exclusive scan ----------------
__global__ __launch_bounds__(256) void scan_p1(const int* __restrict__ a, int* __restrict__ bsums, int n) {
    __shared__ int wsum[4];
    int b = blockIdx.x, t = threadIdx.x;
    int base = b * SCAN_CHUNK;
    int sum = 0;
    #pragma unroll
    for (int j = 0; j < SCAN_CHUNK / 256; ++j) {
        int idx = base + j * 256 + t;
        sum += (idx < n) ? a[idx] : 0;
    }
    #pragma unroll
    for (int off = 32; off; off >>= 1) sum += __shfl_down(sum, off, 64);
    int lane = t & 63, w = t >> 6;
    if (lane == 0) wsum[w] = sum;
    __syncthreads();
    if (t == 0) bsums[b] = wsum[0] + wsum[1] + wsum[2] + wsum[3];
}

__global__ __launch_bounds__(64) void scan_p2(int* __restrict__ bsums, int nb) {
    int t = threadIdx.x;
    int carry = 0;
    for (int base = 0; base < nb; base += 64) {
        int i = base + t;
        int v = (i < nb) ? bsums[i] : 0;
        int inc = v;
        #pragma unroll
        for (int off = 1; off < 64; off <<= 1) {
            int y = __shfl_up(inc, off, 64);
            if (t >= off) inc += y;
        }
        if (i < nb) bsums[i] = carry + inc - v;   // exclusive
        carry += __shfl(inc, 63, 64);
    }
}

__global__ __launch_bounds__(256) void scan_p3(const int* __restrict__ a, const int* __restrict__ bsums,
                                               int* __restrict__ out, int n) {
    __shared__ int wsum[4];
    int b = blockIdx.x, t = threadIdx.x;
    int lane = t & 63, w = t >> 6;
    int i0 = b * SCAN_CHUNK + t * 8;
    int v[8];
    int s = 0;
    #pragma unroll
    for (int j = 0; j < 8; ++j) {
        int idx = i0 + j;
        v[j] = (idx < n) ? a[idx] : 0;
        s += v[j];
    }
    int ps = s;
    #pragma unroll
    for (int off = 1; off < 64; off <<= 1) {
        int y = __shfl_up(ps, off, 64);
        if (lane >= off) ps += y;
    }
    if (lane == 63) wsum[w] = ps;
    __syncthreads();
    if (t == 0) {
        int acc = 0;
        #pragma unroll
        for (int i = 0; i < 4; ++i) { int tmp = wsum[i]; wsum[i] = acc; acc += tmp; }
    }
    __syncthreads();
    int run = (ps - s) + wsum[w] + bsums[b];
    #pragma unroll
    for (int j = 0; j < 8; ++j) {
        int idx = i0 + j;
        if (idx < n) out[idx] = run;
        run += v[j];
    }
}

// ---------------- partition edges into bucket-major record array ----------------
__global__ __launch_bounds__(256) void part_kernel(const int* __restrict__ src, const int* __restrict__ dst,
                                                   const int* __restrict__ offs,
                                                   unsigned long long* __restrict__ recs,
                                                   int nE, int nblk) {
    __shared__ int cur[NB];
    int t = threadIdx.x, blk = blockIdx.x;
    for (int i = t; i < NB; i += 256) cur[i] = offs[i * nblk + blk];
    __syncthreads();
    int base = blk * EPB;
    #pragma unroll
    for (int j = 0; j < EPB / 256; ++j) {
        int e = base + j * 256 + t;
        if (e < nE) {
            int s = src[e], d = dst[e];
            int pos = atomicAdd(&cur[d >> 8], 1);
            recs[pos] = (unsigned long long)(unsigned)s | ((unsigned long long)(unsigned)d << 32);
        }
    }
}

// ---------------- per-bucket CSR build: row_ptr, esrc, dinv (fused) ----------------
__global__ __launch_bounds__(256) void csr_kernel(const unsigned long long* __restrict__ recs,
                                                  const int* __restrict__ offs,
                                                  int* __restrict__ row_ptr, int* __restrict__ esrc,
                                                  float* __restrict__ dinv, int nE, int nblk) {
    __shared__ int cnt[256];
    __shared__ int cur[256];
    __shared__ int wsum[4];
    int b = blockIdx.x, t = threadIdx.x;
    int node0 = b << 8;
    int segBeg = offs[b * nblk];
    int segEnd = (b + 1 < NB) ? offs[(b + 1) * nblk] : nE;
    cnt[t] = 0;
    __syncthreads();
    for (int e = segBeg + t; e < segEnd; e += 256) {
        int d = (int)(recs[e] >> 32);
        atomicAdd(&cnt[d - node0], 1);
    }
    __syncthreads();
    int c = cnt[t];
    int lane = t & 63, w = t >> 6;
    int ps = c;
    #pragma unroll
    for (int off = 1; off < 64; off <<= 1) {
        int y = __shfl_up(ps, off, 64);
        if (lane >= off) ps += y;
    }
    if (lane == 63) wsum[w] = ps;
    __syncthreads();
    if (t == 0) {
        int a = 0;
        #pragma unroll
        for (int i = 0; i < 4; ++i) { int tmp = wsum[i]; wsum[i] = a; a += tmp; }
    }
    __syncthreads();
    int gbase = segBeg + (ps - c) + wsum[w];
    cur[t] = gbase;
    int node = node0 + t;
    if (node < N_NODES) {
        row_ptr[node] = gbase;
        dinv[node] = rsqrtf((float)c + 1.0f);
    }
    if (b == NB - 1 && t == 0) row_ptr[N_NODES] = nE;
    __syncthreads();
    for (int e = segBeg + t; e < segEnd; e += 256) {
        unsigned long long r = recs[e];
        int d = (int)(r >> 32);
        int pos = atomicAdd(&cur[d - node0], 1);
        esrc[pos] = (int)(r & 0xffffffffu);
    }
}

// ---------------- W transpose + cast: WT[n][k] bf16 from W[k][n] f32 ----------------
__global__ __launch_bounds__(256) void wtrans(const float* __restrict__ W, unsigned short* __restrict__ WT) {
    int idx = blockIdx.x * 256 + threadIdx.x;
    int k = idx >> 7, n = idx & 127;
    WT[n * 128 + k] = f2bf(W[idx]);
}

// ---------------- MFMA GEMM: H[nrows x 128](bf16) = X[nrows x 128] @ W[128 x 128] ----------------
template<int IN_F32>
__global__ __launch_bounds__(256) void gemm_mfma(const void* __restrict__ Xv,
                                                 const unsigned short* __restrict__ WT,
                                                 unsigned short* __restrict__ H, int nrows) {
    __shared__ char lds[65536];
    char* xs  = lds;            // 128x128 bf16, swizzled
    char* wsh = lds + 32768;    // WT 128x128 bf16 ([n][k]), swizzled
    int t = threadIdx.x;
    int base = blockIdx.x * 128;

    #pragma unroll
    for (int j = 0; j < 8; ++j) {
        int idx = j * 256 + t;
        int n = idx >> 4, c8 = idx & 15;
        short8 v = *(const short8*)(WT + n * 128 + c8 * 8);
        int off = (n * 256 + c8 * 16) ^ ((n & 7) << 4);
        *(short8*)(wsh + off) = v;
    }
    #pragma unroll
    for (int j = 0; j < 8; ++j) {
        int idx = j * 256 + t;
        int row = idx >> 4, c8 = idx & 15;
        int grow = base + row;
        short8 v = {0,0,0,0,0,0,0,0};
        if (grow < nrows) {
            if (IN_F32) {
                const float* Xf = (const float*)Xv;
                float4 a = *(const float4*)(Xf + (size_t)grow * 128 + c8 * 8);
                float4 b = *(const float4*)(Xf + (size_t)grow * 128 + c8 * 8 + 4);
                v[0] = (short)f2bf(a.x); v[1] = (short)f2bf(a.y);
                v[2] = (short)f2bf(a.z); v[3] = (short)f2bf(a.w);
                v[4] = (short)f2bf(b.x); v[5] = (short)f2bf(b.y);
                v[6] = (short)f2bf(b.z); v[7] = (short)f2bf(b.w);
            } else {
                const unsigned short* Xb = (const unsigned short*)Xv;
                v = *(const short8*)(Xb + (size_t)grow * 128 + c8 * 8);
            }
        }
        int off = (row * 256 + c8 * 16) ^ ((row & 7) << 4);
        *(short8*)(xs + off) = v;
    }
    __syncthreads();

    int lane = t & 63, w = t >> 6;
    int lhi = lane >> 4, llo = lane & 15;
    f32x4 acc[2][8];
    #pragma unroll
    for (int r = 0; r < 2; ++r)
        #pragma unroll
        for (int c = 0; c < 8; ++c) acc[r][c] = (f32x4){0.f, 0.f, 0.f, 0.f};

    #pragma unroll
    for (int kk = 0; kk < 4; ++kk) {
        short8 a[2];
        #pragma unroll
        for (int r = 0; r < 2; ++r) {
            int row = w * 32 + r * 16 + llo;
            int off = (row * 256 + kk * 64 + lhi * 16) ^ ((row & 7) << 4);
            a[r] = *(const short8*)(xs + off);
        }
        #pragma unroll
        for (int c = 0; c < 8; ++c) {
            int col = c * 16 + llo;
            int off = (col * 256 + kk * 64 + lhi * 16) ^ ((col & 7) << 4);
            short8 bb = *(const short8*)(wsh + off);
            acc[0][c] = __builtin_amdgcn_mfma_f32_16x16x32_bf16(a[0], bb, acc[0][c], 0, 0, 0);
            acc[1][c] = __builtin_amdgcn_mfma_f32_16x16x32_bf16(a[1], bb, acc[1][c], 0, 0, 0);
        }
    }

    #pragma unroll
    for (int r = 0; r < 2; ++r) {
        #pragma unroll
        for (int reg = 0; reg < 4; ++reg) {
            int grow = base + w * 32 + r * 16 + lhi * 4 + reg;
            if (grow < nrows) {
                #pragma unroll
                for (int c = 0; c < 8; ++c)
                    H[(size_t)grow * 128 + c * 16 + llo] = f2bf(acc[r][c][reg]);
            }
        }
    }
}

// ---------------- aggregation (bf16), 4 edge-slots x 16 lanes for MLP ----------------
// O = relu( D^-1/2 (A+I) D^-1/2 H + b )
__global__ __launch_bounds__(256) void agg_bf16(const unsigned short* __restrict__ H,
                                                unsigned short* __restrict__ O,
                                                const float* __restrict__ dinv,
                                                const int* __restrict__ row_ptr,
                                                const int* __restrict__ esrc,
                                                const float* __restrict__ bias) {
    int node = blockIdx.x * 4 + (threadIdx.x >> 6);
    if (node >= N_NODES) return;
    int lane = threadIdx.x & 63;
    int g  = lane >> 4;        // edge slot 0..3
    int fl = lane & 15;        // feature chunk: features [fl*8, fl*8+8)

    float dv = dinv[node];
    float acc[8];
    // self-loop term (group 0 only; others start at zero)
    {
        short8 hv = *(const short8*)(H + (size_t)node * FDIM + fl * 8);
        float sw = (g == 0) ? dv * dv : 0.f;
        #pragma unroll
        for (int j = 0; j < 8; ++j) acc[j] = bf2f((unsigned short)hv[j]) * sw;
    }

    int beg = row_ptr[node], end = row_ptr[node + 1];
    for (int e0 = beg; e0 < end; e0 += 4) {
        int e = e0 + g;
        if (e < end) {
            int s = esrc[e];
            float wgt = dinv[s] * dv;
            short8 m = *(const short8*)(H + (size_t)s * FDIM + fl * 8);
            #pragma unroll
            for (int j = 0; j < 8; ++j) acc[j] += bf2f((unsigned short)m[j]) * wgt;
        }
    }

    // reduce across the 4 edge slots
    #pragma unroll
    for (int j = 0; j < 8; ++j) {
        acc[j] += __shfl_xor(acc[j], 16, 64);
        acc[j] += __shfl_xor(acc[j], 32, 64);
    }

    // bias + relu + pack (all lanes compute; lanes<16 write)
    float4 b0 = *(const float4*)(bias + fl * 8);
    float4 b1 = *(const float4*)(bias + fl * 8 + 4);
    float r0 = fmaxf(acc[0] + b0.x, 0.f), r1 = fmaxf(acc[1] + b0.y, 0.f);
    float r2 = fmaxf(acc[2] + b0.z, 0.f), r3 = fmaxf(acc[3] + b0.w, 0.f);
    float r4 = fmaxf(acc[4] + b1.x, 0.f), r5 = fmaxf(acc[5] + b1.y, 0.f);
    float r6 = fmaxf(acc[6] + b1.z, 0.f), r7 = fmaxf(acc[7] + b1.w, 0.f);
    if (g == 0) {
        short8 v;
        v[0] = (short)f2bf(r0); v[1] = (short)f2bf(r1);
        v[2] = (short)f2bf(r2); v[3] = (short)f2bf(r3);
        v[4] = (short)f2bf(r4); v[5] = (short)f2bf(r5);
        v[6] = (short)f2bf(r6); v[7] = (short)f2bf(r7);
        *(short8*)(O + (size_t)node * FDIM + fl * 8) = v;
    }
}

// ---------------- pooling (bf16 input) ----------------
__global__ __launch_bounds__(128) void pool_kernel(const unsigned short* __restrict__ H, const int* __restrict__ batch,
                                                   float* __restrict__ pooled, float* __restrict__ cnt) {
    int f  = threadIdx.x;
    int r0 = blockIdx.x * 128;
    int rend = r0 + 128; if (rend > N_NODES) rend = N_NODES;
    if (r0 >= N_NODES) return;
    float acc = 0.f;
    int g_cur = batch[r0];
    int run = 0;
    for (int r = r0; r < rend; ++r) {
        int g = batch[r];
        if (g != g_cur) {
            atomicAdd(&pooled[g_cur * FDIM + f], acc);
            if (f == 0) atomicAdd(&cnt[g_cur], (float)run);
            acc = 0.f; run = 0; g_cur = g;
        }
        acc += bf2f(H[(size_t)r * FDIM + f]);
        run++;
    }
    atomicAdd(&pooled[g_cur * FDIM + f], acc);
    if (f == 0) atomicAdd(&cnt[g_cur], (float)run);
}

// ---------------- final FC ----------------
__global__ __launch_bounds__(256) void fc_kernel(const float* __restrict__ pooled, const float* __restrict__ cnt,
                                                 const float* __restrict__ fcW, const float* __restrict__ fcb,
                                                 float* __restrict__ out) {
    int idx = blockIdx.x * 256 + threadIdx.x;
    if (idx >= N_GRAPHS * N_CLASSES) return;
    int g = idx >> 5, c = idx & 31;
    float inv = 1.0f / fmaxf(cnt[g], 1.0f);
    float acc = 0.f;
    #pragma unroll 16
    for (int k = 0; k < FDIM; ++k) acc += pooled[g * FDIM + k] * fcW[k * N_CLASSES + c];
    out[idx] = acc * inv + fcb[c];
}

extern "C" void kernel_launch(void* const* d_in, const int* in_sizes, int n_in,
                              void* d_out, int out_size, void* d_ws, size_t ws_size,
                              hipStream_t stream) {
    const float* x    = (const float*)d_in[0];
    const int*   ei   = (const int*)d_in[1];     // [2, E] int32
    const int*   batch= (const int*)d_in[2];
    const float* W1   = (const float*)d_in[3];
    const float* b1   = (const float*)d_in[4];
    const float* W2   = (const float*)d_in[5];
    const float* b2   = (const float*)d_in[6];
    const float* fcW  = (const float*)d_in[7];
    const float* fcb  = (const float*)d_in[8];
    float* out = (float*)d_out;

    const int nE = in_sizes[1] / 2;
    const int* src = ei;
    const int* dst = ei + nE;

    const int nblk  = (nE + EPB - 1) / EPB;
    const int histN = NB * nblk;
    const int sB    = (histN + SCAN_CHUNK - 1) / SCAN_CHUNK;

    // workspace layout
    unsigned short* Hb0 = (unsigned short*)d_ws;                 // N*128 bf16
    unsigned short* Hb1 = Hb0 + (size_t)N_NODES * FDIM;          // N*128 bf16
    unsigned short* W1T = Hb1 + (size_t)N_NODES * FDIM;          // 128*128 bf16
    unsigned short* W2T = W1T + FDIM * FDIM;                     // 128*128 bf16
    float* dinv    = (float*)(W2T + FDIM * FDIM);                // N
    int*   row_ptr = (int*)(dinv + N_NODES);                     // N+1
    int*   esrc    = row_ptr + N_NODES + 1;                      // E
    unsigned long long* recs = (unsigned long long*)(esrc + ((nE + 1) & ~1)); // E (8B aligned)
    int*   hist    = (int*)(recs + nE);                          // NB*nblk
    int*   bsums   = hist + histN;                               // sB
    float* pooled  = (float*)(bsums + ((sB + 1) & ~1));          // G*F
    float* cnt     = pooled + N_GRAPHS * FDIM;                   // G

    hipMemsetAsync(pooled, 0, (N_GRAPHS * FDIM + N_GRAPHS) * sizeof(float), stream);

    wtrans<<<64, 256, 0, stream>>>(W1, W1T);
    wtrans<<<64, 256, 0, stream>>>(W2, W2T);

    // CSR build: hist -> scan -> partition -> per-bucket CSR (+dinv)
    hist_kernel<<<nblk, 256, 0, stream>>>(dst, hist, nE, nblk);
    scan_p1<<<sB, 256, 0, stream>>>(hist, bsums, histN);
    scan_p2<<<1, 64, 0, stream>>>(bsums, sB);
    scan_p3<<<sB, 256, 0, stream>>>(hist, bsums, hist, histN);
    part_kernel<<<nblk, 256, 0, stream>>>(src, dst, hist, recs, nE, nblk);
    csr_kernel<<<NB, 256, 0, stream>>>(recs, hist, row_ptr, esrc, dinv, nE, nblk);

    const int gemm_grid = (N_NODES + 127) / 128;
    // layer 1
    gemm_mfma<1><<<gemm_grid, 256, 0, stream>>>(x, W1T, Hb0, N_NODES);
    agg_bf16<<<(N_NODES + 3) / 4, 256, 0, stream>>>(Hb0, Hb1, dinv, row_ptr, esrc, b1);
    // layer 2
    gemm_mfma<0><<<gemm_grid, 256, 0, stream>>>(Hb1, W2T, Hb0, N_NODES);
    agg_bf16<<<(N_NODES + 3) / 4, 256, 0, stream>>>(Hb0, Hb1, dinv, row_ptr, esrc, b2);

    // pool + fc
    pool_kernel<<<(N_NODES + 127) / 128, 128, 0, stream>>>(Hb1, batch, pooled, cnt);
    fc_kernel<<<(N_GRAPHS * N_CLASSES + 255) / 256, 256, 0, stream>>>(pooled, cnt, fcW, fcb, out);
}

// Round 8
// 400.015 us; speedup vs baseline: 2.2087x; 1.0104x over previous
//
#include <hip/hip_runtime.h>
#include <hip/hip_bf16.h>

#define N_NODES   100000
#define FDIM      128
#define N_GRAPHS  64
#define N_CLASSES 32

#define NB        ((N_NODES + 255) / 256)     // 391 buckets of 256 nodes
#define EPB       8192                         // edges per block (hist/part)
#define SCAN_CHUNK 2048

typedef __attribute__((ext_vector_type(8))) short short8;
typedef __attribute__((ext_vector_type(4))) float f32x4;

__device__ __forceinline__ float bf2f(unsigned int u16) {
    unsigned int x = u16 << 16;
    return __builtin_bit_cast(float, x);
}
__device__ __forceinline__ unsigned short f2bf(float f) {
    unsigned int u = __builtin_bit_cast(unsigned int, f);
    unsigned int r = (u + 0x7fffu + ((u >> 16) & 1u)) >> 16;   // RNE
    return (unsigned short)r;
}

// ---------------- bucket histogram: hist[bucket * nblk + blk] ----------------
__global__ __launch_bounds__(256) void hist_kernel(const int* __restrict__ dst, int* __restrict__ hist,
                                                   int nE, int nblk) {
    __shared__ int h[NB];
    int t = threadIdx.x, blk = blockIdx.x;
    for (int i = t; i < NB; i += 256) h[i] = 0;
    __syncthreads();
    int base = blk * EPB;
    #pragma unroll
    for (int j = 0; j < EPB / 256; ++j) {
        int e = base + j * 256 + t;
        if (e < nE) atomicAdd(&h[dst[e] >> 8], 1);
    }
    __syncthreads();
    for (int i = t; i < NB; i += 256) hist[i * nblk + blk] = h[i];
}

// ---------------- generic two-level exclusive scan ----------------
__global__ __launch_bounds__(256) void scan_p1(const int* __restrict__ a, int* __restrict__ bsums, int n) {
    __shared__ int wsum[4];
    int b = blockIdx.x, t = threadIdx.x;
    int base = b * SCAN_CHUNK;
    int sum = 0;
    #pragma unroll
    for (int j = 0; j < SCAN_CHUNK / 256; ++j) {
        int idx = base + j * 256 + t;
        sum += (idx < n) ? a[idx] : 0;
    }
    #pragma unroll
    for (int off = 32; off; off >>= 1) sum += __shfl_down(sum, off, 64);
    int lane = t & 63, w = t >> 6;
    if (lane == 0) wsum[w] = sum;
    __syncthreads();
    if (t == 0) bsums[b] = wsum[0] + wsum[1] + wsum[2] + wsum[3];
}

__global__ __launch_bounds__(64) void scan_p2(int* __restrict__ bsums, int nb) {
    int t = threadIdx.x;
    int carry = 0;
    for (int base = 0; base < nb; base += 64) {
        int i = base + t;
        int v = (i < nb) ? bsums[i] : 0;
        int inc = v;
        #pragma unroll
        for (int off = 1; off < 64; off <<= 1) {
            int y = __shfl_up(inc, off, 64);
            if (t >= off) inc += y;
        }
        if (i < nb) bsums[i] = carry + inc - v;   // exclusive
        carry += __shfl(inc, 63, 64);
    }
}

__global__ __launch_bounds__(256) void scan_p3(const int* __restrict__ a, const int* __restrict__ bsums,
                                               int* __restrict__ out, int n) {
    __shared__ int wsum[4];
    int b = blockIdx.x, t = threadIdx.x;
    int lane = t & 63, w = t >> 6;
    int i0 = b * SCAN_CHUNK + t * 8;
    int v[8];
    int s = 0;
    #pragma unroll
    for (int j = 0; j < 8; ++j) {
        int idx = i0 + j;
        v[j] = (idx < n) ? a[idx] : 0;
        s += v[j];
    }
    int ps = s;
    #pragma unroll
    for (int off = 1; off < 64; off <<= 1) {
        int y = __shfl_up(ps, off, 64);
        if (lane >= off) ps += y;
    }
    if (lane == 63) wsum[w] = ps;
    __syncthreads();
    if (t == 0) {
        int acc = 0;
        #pragma unroll
        for (int i = 0; i < 4; ++i) { int tmp = wsum[i]; wsum[i] = acc; acc += tmp; }
    }
    __syncthreads();
    int run = (ps - s) + wsum[w] + bsums[b];
    #pragma unroll
    for (int j = 0; j < 8; ++j) {
        int idx = i0 + j;
        if (idx < n) out[idx] = run;
        run += v[j];
    }
}

// ---------------- partition edges into bucket-major record array ----------------
__global__ __launch_bounds__(256) void part_kernel(const int* __restrict__ src, const int* __restrict__ dst,
                                                   const int* __restrict__ offs,
                                                   unsigned long long* __restrict__ recs,
                                                   int nE, int nblk) {
    __shared__ int cur[NB];
    int t = threadIdx.x, blk = blockIdx.x;
    for (int i = t; i < NB; i += 256) cur[i] = offs[i * nblk + blk];
    __syncthreads();
    int base = blk * EPB;
    #pragma unroll
    for (int j = 0; j < EPB / 256; ++j) {
        int e = base + j * 256 + t;
        if (e < nE) {
            int s = src[e], d = dst[e];
            int pos = atomicAdd(&cur[d >> 8], 1);
            recs[pos] = (unsigned long long)(unsigned)s | ((unsigned long long)(unsigned)d << 32);
        }
    }
}

// ---------------- per-bucket CSR build: row_ptr, esrc, dinv (fused) ----------------
__global__ __launch_bounds__(256) void csr_kernel(const unsigned long long* __restrict__ recs,
                                                  const int* __restrict__ offs,
                                                  int* __restrict__ row_ptr, int* __restrict__ esrc,
                                                  float* __restrict__ dinv, int nE, int nblk) {
    __shared__ int cnt[256];
    __shared__ int cur[256];
    __shared__ int wsum[4];
    int b = blockIdx.x, t = threadIdx.x;
    int node0 = b << 8;
    int segBeg = offs[b * nblk];
    int segEnd = (b + 1 < NB) ? offs[(b + 1) * nblk] : nE;
    cnt[t] = 0;
    __syncthreads();
    for (int e = segBeg + t; e < segEnd; e += 256) {
        int d = (int)(recs[e] >> 32);
        atomicAdd(&cnt[d - node0], 1);
    }
    __syncthreads();
    int c = cnt[t];
    int lane = t & 63, w = t >> 6;
    int ps = c;
    #pragma unroll
    for (int off = 1; off < 64; off <<= 1) {
        int y = __shfl_up(ps, off, 64);
        if (lane >= off) ps += y;
    }
    if (lane == 63) wsum[w] = ps;
    __syncthreads();
    if (t == 0) {
        int a = 0;
        #pragma unroll
        for (int i = 0; i < 4; ++i) { int tmp = wsum[i]; wsum[i] = a; a += tmp; }
    }
    __syncthreads();
    int gbase = segBeg + (ps - c) + wsum[w];
    cur[t] = gbase;
    int node = node0 + t;
    if (node < N_NODES) {
        row_ptr[node] = gbase;
        dinv[node] = rsqrtf((float)c + 1.0f);
    }
    if (b == NB - 1 && t == 0) row_ptr[N_NODES] = nE;
    __syncthreads();
    for (int e = segBeg + t; e < segEnd; e += 256) {
        unsigned long long r = recs[e];
        int d = (int)(r >> 32);
        int pos = atomicAdd(&cur[d - node0], 1);
        esrc[pos] = (int)(r & 0xffffffffu);
    }
}

// ---------------- W transpose + cast: WT[n][k] bf16 from W[k][n] f32 ----------------
__global__ __launch_bounds__(256) void wtrans(const float* __restrict__ W, unsigned short* __restrict__ WT) {
    int idx = blockIdx.x * 256 + threadIdx.x;
    int k = idx >> 7, n = idx & 127;
    WT[n * 128 + k] = f2bf(W[idx]);
}

// ---------------- MFMA GEMM: H[nrows x 128](bf16) = X[nrows x 128] @ W[128 x 128] ----------------
template<int IN_F32>
__global__ __launch_bounds__(256) void gemm_mfma(const void* __restrict__ Xv,
                                                 const unsigned short* __restrict__ WT,
                                                 unsigned short* __restrict__ H, int nrows) {
    __shared__ char lds[65536];
    char* xs  = lds;            // 128x128 bf16, swizzled
    char* wsh = lds + 32768;    // WT 128x128 bf16 ([n][k]), swizzled
    int t = threadIdx.x;
    int base = blockIdx.x * 128;

    #pragma unroll
    for (int j = 0; j < 8; ++j) {
        int idx = j * 256 + t;
        int n = idx >> 4, c8 = idx & 15;
        short8 v = *(const short8*)(WT + n * 128 + c8 * 8);
        int off = (n * 256 + c8 * 16) ^ ((n & 7) << 4);
        *(short8*)(wsh + off) = v;
    }
    #pragma unroll
    for (int j = 0; j < 8; ++j) {
        int idx = j * 256 + t;
        int row = idx >> 4, c8 = idx & 15;
        int grow = base + row;
        short8 v = {0,0,0,0,0,0,0,0};
        if (grow < nrows) {
            if (IN_F32) {
                const float* Xf = (const float*)Xv;
                float4 a = *(const float4*)(Xf + (size_t)grow * 128 + c8 * 8);
                float4 b = *(const float4*)(Xf + (size_t)grow * 128 + c8 * 8 + 4);
                v[0] = (short)f2bf(a.x); v[1] = (short)f2bf(a.y);
                v[2] = (short)f2bf(a.z); v[3] = (short)f2bf(a.w);
                v[4] = (short)f2bf(b.x); v[5] = (short)f2bf(b.y);
                v[6] = (short)f2bf(b.z); v[7] = (short)f2bf(b.w);
            } else {
                const unsigned short* Xb = (const unsigned short*)Xv;
                v = *(const short8*)(Xb + (size_t)grow * 128 + c8 * 8);
            }
        }
        int off = (row * 256 + c8 * 16) ^ ((row & 7) << 4);
        *(short8*)(xs + off) = v;
    }
    __syncthreads();

    int lane = t & 63, w = t >> 6;
    int lhi = lane >> 4, llo = lane & 15;
    f32x4 acc[2][8];
    #pragma unroll
    for (int r = 0; r < 2; ++r)
        #pragma unroll
        for (int c = 0; c < 8; ++c) acc[r][c] = (f32x4){0.f, 0.f, 0.f, 0.f};

    #pragma unroll
    for (int kk = 0; kk < 4; ++kk) {
        short8 a[2];
        #pragma unroll
        for (int r = 0; r < 2; ++r) {
            int row = w * 32 + r * 16 + llo;
            int off = (row * 256 + kk * 64 + lhi * 16) ^ ((row & 7) << 4);
            a[r] = *(const short8*)(xs + off);
        }
        #pragma unroll
        for (int c = 0; c < 8; ++c) {
            int col = c * 16 + llo;
            int off = (col * 256 + kk * 64 + lhi * 16) ^ ((col & 7) << 4);
            short8 bb = *(const short8*)(wsh + off);
            acc[0][c] = __builtin_amdgcn_mfma_f32_16x16x32_bf16(a[0], bb, acc[0][c], 0, 0, 0);
            acc[1][c] = __builtin_amdgcn_mfma_f32_16x16x32_bf16(a[1], bb, acc[1][c], 0, 0, 0);
        }
    }

    #pragma unroll
    for (int r = 0; r < 2; ++r) {
        #pragma unroll
        for (int reg = 0; reg < 4; ++reg) {
            int grow = base + w * 32 + r * 16 + lhi * 4 + reg;
            if (grow < nrows) {
                #pragma unroll
                for (int c = 0; c < 8; ++c)
                    H[(size_t)grow * 128 + c * 16 + llo] = f2bf(acc[r][c][reg]);
            }
        }
    }
}

// ---------------- aggregation (bf16): 4 edge-slots x 16 lanes, x4 unroll (16 edges in flight) ----------------
// O = relu( D^-1/2 (A+I) D^-1/2 H + b )
__global__ __launch_bounds__(256) void agg_bf16(const unsigned short* __restrict__ H,
                                                unsigned short* __restrict__ O,
                                                const float* __restrict__ dinv,
                                                const int* __restrict__ row_ptr,
                                                const int* __restrict__ esrc,
                                                const float* __restrict__ bias) {
    int node = blockIdx.x * 4 + (threadIdx.x >> 6);
    if (node >= N_NODES) return;
    int lane = threadIdx.x & 63;
    int g  = lane >> 4;        // edge slot 0..3
    int fl = lane & 15;        // feature chunk: features [fl*8, fl*8+8)

    float dv = dinv[node];
    float acc[8];
    // self-loop term (group 0 only; others start at zero)
    {
        short8 hv = *(const short8*)(H + (size_t)node * FDIM + fl * 8);
        float sw = (g == 0) ? dv * dv : 0.f;
        #pragma unroll
        for (int j = 0; j < 8; ++j) acc[j] = bf2f((unsigned short)hv[j]) * sw;
    }

    int beg = row_ptr[node], end = row_ptr[node + 1];
    // 16 edges per iteration: slot g owns edges [e0+4g, e0+4g+4)
    for (int e0 = beg; e0 < end; e0 += 16) {
        int eb = e0 + g * 4;
        int s[4];
        float wg[4];
        #pragma unroll
        for (int u = 0; u < 4; ++u) {
            int e = eb + u;
            int ee = min(e, end - 1);           // clamp: tail lanes re-read a hot row (coalesced)
            s[u] = esrc[ee];
            wg[u] = (e < end) ? dinv[s[u]] * dv : 0.f;
        }
        #pragma unroll
        for (int u = 0; u < 4; ++u) {
            short8 m = *(const short8*)(H + (size_t)s[u] * FDIM + fl * 8);
            float wgt = wg[u];
            #pragma unroll
            for (int j = 0; j < 8; ++j) acc[j] += bf2f((unsigned short)m[j]) * wgt;
        }
    }

    // reduce across the 4 edge slots
    #pragma unroll
    for (int j = 0; j < 8; ++j) {
        acc[j] += __shfl_xor(acc[j], 16, 64);
        acc[j] += __shfl_xor(acc[j], 32, 64);
    }

    // bias + relu + pack (all lanes compute; slot-0 lanes write)
    float4 b0 = *(const float4*)(bias + fl * 8);
    float4 b1 = *(const float4*)(bias + fl * 8 + 4);
    float r0 = fmaxf(acc[0] + b0.x, 0.f), r1 = fmaxf(acc[1] + b0.y, 0.f);
    float r2 = fmaxf(acc[2] + b0.z, 0.f), r3 = fmaxf(acc[3] + b0.w, 0.f);
    float r4 = fmaxf(acc[4] + b1.x, 0.f), r5 = fmaxf(acc[5] + b1.y, 0.f);
    float r6 = fmaxf(acc[6] + b1.z, 0.f), r7 = fmaxf(acc[7] + b1.w, 0.f);
    if (g == 0) {
        short8 v;
        v[0] = (short)f2bf(r0); v[1] = (short)f2bf(r1);
        v[2] = (short)f2bf(r2); v[3] = (short)f2bf(r3);
        v[4] = (short)f2bf(r4); v[5] = (short)f2bf(r5);
        v[6] = (short)f2bf(r6); v[7] = (short)f2bf(r7);
        *(short8*)(O + (size_t)node * FDIM + fl * 8) = v;
    }
}

// ---------------- pooling (bf16 input) ----------------
__global__ __launch_bounds__(128) void pool_kernel(const unsigned short* __restrict__ H, const int* __restrict__ batch,
                                                   float* __restrict__ pooled, float* __restrict__ cnt) {
    int f  = threadIdx.x;
    int r0 = blockIdx.x * 128;
    int rend = r0 + 128; if (rend > N_NODES) rend = N_NODES;
    if (r0 >= N_NODES) return;
    float acc = 0.f;
    int g_cur = batch[r0];
    int run = 0;
    for (int r = r0; r < rend; ++r) {
        int g = batch[r];
        if (g != g_cur) {
            atomicAdd(&pooled[g_cur * FDIM + f], acc);
            if (f == 0) atomicAdd(&cnt[g_cur], (float)run);
            acc = 0.f; run = 0; g_cur = g;
        }
        acc += bf2f(H[(size_t)r * FDIM + f]);
        run++;
    }
    atomicAdd(&pooled[g_cur * FDIM + f], acc);
    if (f == 0) atomicAdd(&cnt[g_cur], (float)run);
}

// ---------------- final FC ----------------
__global__ __launch_bounds__(256) void fc_kernel(const float* __restrict__ pooled, const float* __restrict__ cnt,
                                                 const float* __restrict__ fcW, const float* __restrict__ fcb,
                                                 float* __restrict__ out) {
    int idx = blockIdx.x * 256 + threadIdx.x;
    if (idx >= N_GRAPHS * N_CLASSES) return;
    int g = idx >> 5, c = idx & 31;
    float inv = 1.0f / fmaxf(cnt[g], 1.0f);
    float acc = 0.f;
    #pragma unroll 16
    for (int k = 0; k < FDIM; ++k) acc += pooled[g * FDIM + k] * fcW[k * N_CLASSES + c];
    out[idx] = acc * inv + fcb[c];
}

extern "C" void kernel_launch(void* const* d_in, const int* in_sizes, int n_in,
                              void* d_out, int out_size, void* d_ws, size_t ws_size,
                              hipStream_t stream) {
    const float* x    = (const float*)d_in[0];
    const int*   ei   = (const int*)d_in[1];     // [2, E] int32
    const int*   batch= (const int*)d_in[2];
    const float* W1   = (const float*)d_in[3];
    const float* b1   = (const float*)d_in[4];
    const float* W2   = (const float*)d_in[5];
    const float* b2   = (const float*)d_in[6];
    const float* fcW  = (const float*)d_in[7];
    const float* fcb  = (const float*)d_in[8];
    float* out = (float*)d_out;

    const int nE = in_sizes[1] / 2;
    const int* src = ei;
    const int* dst = ei + nE;

    const int nblk  = (nE + EPB - 1) / EPB;
    const int histN = NB * nblk;
    const int sB    = (histN + SCAN_CHUNK - 1) / SCAN_CHUNK;

    // workspace layout
    unsigned short* Hb0 = (unsigned short*)d_ws;                 // N*128 bf16
    unsigned short* Hb1 = Hb0 + (size_t)N_NODES * FDIM;          // N*128 bf16
    unsigned short* W1T = Hb1 + (size_t)N_NODES * FDIM;          // 128*128 bf16
    unsigned short* W2T = W1T + FDIM * FDIM;                     // 128*128 bf16
    float* dinv    = (float*)(W2T + FDIM * FDIM);                // N
    int*   row_ptr = (int*)(dinv + N_NODES);                     // N+1
    int*   esrc    = row_ptr + N_NODES + 1;                      // E
    unsigned long long* recs = (unsigned long long*)(esrc + ((nE + 1) & ~1)); // E (8B aligned)
    int*   hist    = (int*)(recs + nE);                          // NB*nblk
    int*   bsums   = hist + histN;                               // sB
    float* pooled  = (float*)(bsums + ((sB + 1) & ~1));          // G*F
    float* cnt     = pooled + N_GRAPHS * FDIM;                   // G

    hipMemsetAsync(pooled, 0, (N_GRAPHS * FDIM + N_GRAPHS) * sizeof(float), stream);

    wtrans<<<64, 256, 0, stream>>>(W1, W1T);
    wtrans<<<64, 256, 0, stream>>>(W2, W2T);

    // CSR build: hist -> scan -> partition -> per-bucket CSR (+dinv)
    hist_kernel<<<nblk, 256, 0, stream>>>(dst, hist, nE, nblk);
    scan_p1<<<sB, 256, 0, stream>>>(hist, bsums, histN);
    scan_p2<<<1, 64, 0, stream>>>(bsums, sB);
    scan_p3<<<sB, 256, 0, stream>>>(hist, bsums, hist, histN);
    part_kernel<<<nblk, 256, 0, stream>>>(src, dst, hist, recs, nE, nblk);
    csr_kernel<<<NB, 256, 0, stream>>>(recs, hist, row_ptr, esrc, dinv, nE, nblk);

    const int gemm_grid = (N_NODES + 127) / 128;
    // layer 1
    gemm_mfma<1><<<gemm_grid, 256, 0, stream>>>(x, W1T, Hb0, N_NODES);
    agg_bf16<<<(N_NODES + 3) / 4, 256, 0, stream>>>(Hb0, Hb1, dinv, row_ptr, esrc, b1);
    // layer 2
    gemm_mfma<0><<<gemm_grid, 256, 0, stream>>>(Hb1, W2T, Hb0, N_NODES);
    agg_bf16<<<(N_NODES + 3) / 4, 256, 0, stream>>>(Hb0, Hb1, dinv, row_ptr, esrc, b2);

    // pool + fc
    pool_kernel<<<(N_NODES + 127) / 128, 128, 0, stream>>>(Hb1, batch, pooled, cnt);
    fc_kernel<<<(N_GRAPHS * N_CLASSES + 255) / 256, 256, 0, stream>>>(pooled, cnt, fcW, fcb, out);
}